// Round 16
// baseline (133.833 us; speedup 1.0000x reference)
//
#include <hip/hip_runtime.h>
#include <math.h>

typedef unsigned short u16;
typedef __attribute__((ext_vector_type(8))) short frag_ab;  // 8 bf16
typedef __attribute__((ext_vector_type(4))) float frag_cd;  // 4 fp32

#define BATCH 8
#define NN 128
#define FS 128
#define FV 64
#define NB 8
#define HID 64
#define ROUT 320
#define HSTRB 72    // hid bf16 LDS row stride (shorts)

// ---- ws layout (float offsets); s:[b][f][n], V:[b][f*3+c3][n], t:[b][g][n] ----
#define SZ_S (BATCH*FS*NN)
#define SZ_V (BATCH*FV*3*NN)
#define SZ_T (BATCH*FV*NN)
#define N_W2B (ROUT*HID)            // ushort count (layer-1 Wr2 in bf16)
#define OFF_SB 0
#define OFF_VB (OFF_SB+SZ_S)
#define OFF_T1 (OFF_VB+SZ_V)
#define OFF_W2B (OFF_T1+SZ_T)

__device__ __forceinline__ float silu_f(float x){ return x * (1.0f/(1.0f + __expf(-x))); }

__device__ __forceinline__ u16 f2bf(float x){
  union { float f; unsigned int u; } v; v.f = x;
  unsigned int r = v.u + 0x7fffu + ((v.u >> 16) & 1u);
  return (u16)(r >> 16);
}
__device__ __forceinline__ float bf2f(u16 h){
  union { unsigned int u; float f; } v; v.u = ((unsigned int)h) << 16; return v.f;
}

// ---------------- Layer 0 (specialized): FOUR receivers per block ----------------
// grid = BATCH*NN/4 = 256 (1 block/CU); block 512. s=species (uniform), V=0, t uniform.
// All weight loads (Wr2, WmixS/V, Wsv) shared across 4 receivers; float4 state stores.
__global__ __launch_bounds__(512) void layer0_kernel(
    const float* __restrict__ pos,
    const float* __restrict__ species,  // (128)
    const float* __restrict__ Wr1l,     // (8,64) layer0
    const float* __restrict__ Wr2,      // (2,64,320) fp32
    const float* __restrict__ Wsv,      // (2,128,64)
    const float* __restrict__ WmixSl,   // (192,128) layer0
    const float* __restrict__ WmixVl,   // (128,64) layer0
    float* __restrict__ sOut,           // [b][f][n]
    float* __restrict__ vOut,           // [b][f*3+c3][n]
    float* __restrict__ tOut,           // [b][g][n]
    u16*   __restrict__ w2b)            // (320,64) bf16 c-major, layer1
{
  const int tid = threadIdx.x;
  const int b   = blockIdx.x >> 5;
  const int k0  = (blockIdx.x & 31) * 4;

  __shared__ u16   hidB[4][128*HSTRB];     // 73.7 KB
  __shared__ float vhx[4][128], vhy[4][128], vhz[4][128];
  __shared__ float colsum[4][4][64];
  __shared__ float aggS[4][128];
  __shared__ float dV[4][192];
  __shared__ float sNew[4][128];
  __shared__ float t0L[64];

  const float* pb   = pos + b*NN*3;
  const float* Wr2l = Wr2;

  // ---- phase 0: tid = kk*128 + i; full hid row per thread ----
  {
    const int kk = tid >> 7;
    const int i  = tid & 127;
    const int k  = k0 + kk;
    float vx = pb[k*3+0]-pb[i*3+0];
    float vy = pb[k*3+1]-pb[i*3+1];
    float vz = pb[k*3+2]-pb[i*3+2];
    float r = sqrtf(vx*vx+vy*vy+vz*vz) + 1e-8f;
    float inv = 1.0f/r;
    vhx[kk][i]=vx*inv; vhy[kk][i]=vy*inv; vhz[kk][i]=vz*inv;
    float u = r*0.2f;
    float env = 0.0f;
    if (u < 1.0f && i != k){
      float u2=u*u, u6=u2*u2*u2;
      env = 1.0f - 28.0f*u6 + 48.0f*u6*u - 21.0f*u6*u2;
    }
    float coef = 0.6324555320336759f * inv * env;
    float th   = r * 0.6283185307179586f;
    float s1 = __sinf(th), c1 = __cosf(th);
    float rb[NB];
    rb[0] = coef*s1;
    float twoc = 2.f*c1, sp = s1, spp = 0.f;
    #pragma unroll
    for(int n=1;n<NB;n++){ float s = twoc*sp - spp; spp = sp; sp = s; rb[n] = coef*s; }
    u16* hrow = hidB[kk] + i*HSTRB;
    #pragma unroll
    for(int jg=0;jg<16;jg++){
      float h0=0.f,h1=0.f,h2=0.f,h3=0.f;
      #pragma unroll
      for(int n=0;n<NB;n++){
        const float* wr = Wr1l + n*HID + jg*4;
        float rn = rb[n];
        h0 = fmaf(rn, wr[0], h0);
        h1 = fmaf(rn, wr[1], h1);
        h2 = fmaf(rn, wr[2], h2);
        h3 = fmaf(rn, wr[3], h3);
      }
      ushort4 uu = make_ushort4(f2bf(silu_f(h0)), f2bf(silu_f(h1)),
                                f2bf(silu_f(h2)), f2bf(silu_f(h3)));
      *(ushort4*)(hrow + jg*4) = uu;
    }
  }
  __syncthreads();

  // ---- phase A: colsum — 1024 jobs over 512 threads ----
  for (int t2=tid; t2<1024; t2+=512){
    const int kk  = t2 >> 8;
    const int var = (t2 >> 6) & 3;
    const int j   = t2 & 63;
    const u16* hb = hidB[kk];
    float a0 = 0.f, a1 = 0.f;
    if (var == 0){
      #pragma unroll 8
      for (int i=0;i<128;i+=2){
        a0 += bf2f(hb[i*HSTRB + j]);
        a1 += bf2f(hb[(i+1)*HSTRB + j]);
      }
    } else {
      const float* wv = (var==1) ? vhx[kk] : (var==2) ? vhy[kk] : vhz[kk];
      #pragma unroll 8
      for (int i=0;i<128;i+=2){
        a0 = fmaf(bf2f(hb[i*HSTRB + j]),     wv[i],   a0);
        a1 = fmaf(bf2f(hb[(i+1)*HSTRB + j]), wv[i+1], a1);
      }
    }
    colsum[kk][var][j] = a0+a1;
  }
  __syncthreads();

  // ---- phase B (disjoint): s-proj | V-proj | t0L | w2b conversion ----
  if (tid < 128){
    const int c = tid;
    float d0=0.f,d1=0.f,d2=0.f,d3=0.f;
    #pragma unroll 8
    for (int j=0;j<HID;j++){
      float w0 = Wr2l[j*ROUT + c];
      d0 = fmaf(colsum[0][0][j], w0, d0);
      d1 = fmaf(colsum[1][0][j], w0, d1);
      d2 = fmaf(colsum[2][0][j], w0, d2);
      d3 = fmaf(colsum[3][0][j], w0, d3);
    }
    float sc = species[c] * (1.0f/128.0f);
    aggS[0][c] = sc*d0; aggS[1][c] = sc*d1;
    aggS[2][c] = sc*d2; aggS[3][c] = sc*d3;
  } else if (tid < 320){
    const int o = tid - 128;
    const int f = o & 63, c3 = o >> 6;
    float d0=0.f,d1=0.f,d2=0.f,d3=0.f;
    #pragma unroll 8
    for (int j=0;j<HID;j++){
      float w0 = Wr2l[j*ROUT + 192 + f];
      d0 = fmaf(colsum[0][1+c3][j], w0, d0);
      d1 = fmaf(colsum[1][1+c3][j], w0, d1);
      d2 = fmaf(colsum[2][1+c3][j], w0, d2);
      d3 = fmaf(colsum[3][1+c3][j], w0, d3);
    }
    dV[0][f*3+c3] = d0*(1.0f/128.0f); dV[1][f*3+c3] = d1*(1.0f/128.0f);
    dV[2][f*3+c3] = d2*(1.0f/128.0f); dV[3][f*3+c3] = d3*(1.0f/128.0f);
  } else if (tid < 384){
    const int g = tid - 320;
    float a0=0.f, a1=0.f;
    #pragma unroll 8
    for (int c=0; c<FS; c+=2){
      a0 = fmaf(species[c],   Wsv[c*FV+g],     a0);
      a1 = fmaf(species[c+1], Wsv[(c+1)*FV+g], a1);
    }
    t0L[g] = a0+a1;
  } else if (tid < 464){
    // convert this block's 80-elem slice of Wr2[layer1] to bf16 (256*80 = 20480)
    const int t = blockIdx.x*80 + (tid-384);
    const int j = t & 63, c = t >> 6;
    w2b[t] = f2bf(Wr2[HID*ROUT + j*ROUT + c]);
  }
  __syncthreads();

  // ---- E1 (disjoint): s update | V update — quad receivers, shared weights ----
  if (tid < FS){
    float a0=0.f,a1=0.f,a2=0.f,a3=0.f;
    #pragma unroll 8
    for (int cc=0; cc<128; cc++){
      float w0 = WmixSl[cc*FS+tid];
      a0 = fmaf(aggS[0][cc], w0, a0);
      a1 = fmaf(aggS[1][cc], w0, a1);
      a2 = fmaf(aggS[2][cc], w0, a2);
      a3 = fmaf(aggS[3][cc], w0, a3);
    }
    float sn0 = species[tid] + silu_f(a0);
    float sn1 = species[tid] + silu_f(a1);
    float sn2 = species[tid] + silu_f(a2);
    float sn3 = species[tid] + silu_f(a3);
    sNew[0][tid]=sn0; sNew[1][tid]=sn1; sNew[2][tid]=sn2; sNew[3][tid]=sn3;
    *(float4*)&sOut[(b*FS+tid)*NN + k0] = make_float4(sn0,sn1,sn2,sn3);
  } else if (tid < 320){
    const int o = tid - 128;
    const int g = o/3, c3 = o - g*3;
    float a0=0.f,a1=0.f,a2=0.f,a3=0.f;
    #pragma unroll 8
    for (int f=0; f<FV; f++){
      float w = WmixVl[f*FV+g] * t0L[f];
      a0 = fmaf(dV[0][f*3+c3], w, a0);
      a1 = fmaf(dV[1][f*3+c3], w, a1);
      a2 = fmaf(dV[2][f*3+c3], w, a2);
      a3 = fmaf(dV[3][f*3+c3], w, a3);
    }
    *(float4*)&vOut[(b*FV*3 + o)*NN + k0] = make_float4(a0,a1,a2,a3);
  }
  __syncthreads();

  // ---- E2: t for layer 1 (from updated s), quad receivers ----
  if (tid < FV){
    const float* Wsv1 = Wsv + FS*FV;
    float a0=0.f,a1=0.f,a2=0.f,a3=0.f;
    #pragma unroll 8
    for (int f=0; f<FS; f++){
      float w0 = Wsv1[f*FV+tid];
      a0 = fmaf(sNew[0][f], w0, a0);
      a1 = fmaf(sNew[1][f], w0, a1);
      a2 = fmaf(sNew[2][f], w0, a2);
      a3 = fmaf(sNew[3][f], w0, a3);
    }
    *(float4*)&tOut[(b*FV+tid)*NN + k0] = make_float4(a0,a1,a2,a3);
  }
}

// ---------------- Layer 1 (final): FOUR receivers per block (R15 proven) ----------------
__global__ __launch_bounds__(512) void layer_kernel(
    const float* __restrict__ pos,
    const float* __restrict__ sIn,    // [b][f][n]
    const float* __restrict__ vIn,    // [b][f*3+c3][n]
    const float* __restrict__ tIn,    // [b][g][n]
    const float* __restrict__ Wr1l,   // (8,64) layer1
    const u16*   __restrict__ w2bl,   // (320,64) bf16, c-major
    const float* __restrict__ WmixSl, // (192,128)
    const float* __restrict__ WmixVl, // (128,64)
    const float* __restrict__ WoutS,
    const float* __restrict__ WoutV,
    float* __restrict__ outp)
{
  const int tid  = threadIdx.x;
  const int b    = blockIdx.x >> 5;
  const int k0   = (blockIdx.x & 31) * 4;     // receivers k0..k0+3
  const int w    = tid >> 6;
  const int lane = tid & 63;
  const int col  = lane & 15;
  const int quad = lane >> 4;
  const int wq   = w & 3;
  const int sh   = w >> 2;

  __shared__ u16   hidB[4][128*HSTRB];        // 73.7 KB
  __shared__ float vhx[4][128], vhy[4][128], vhz[4][128];
  __shared__ float aggP[4][2][576];           // 18.4 KB
  __shared__ float sPart[4][2][FS];
  __shared__ float sNew[4][FS];
  __shared__ float vNewL[4][192];
  __shared__ float comL[3];

  const float* pb = pos + b*NN*3;

  // ---- phase 0: tid = kk*128 + i; full hid row per thread ----
  {
    const int kk = tid >> 7;
    const int i  = tid & 127;
    const int k  = k0 + kk;
    float vx = pb[k*3+0]-pb[i*3+0];
    float vy = pb[k*3+1]-pb[i*3+1];
    float vz = pb[k*3+2]-pb[i*3+2];
    float r = sqrtf(vx*vx+vy*vy+vz*vz) + 1e-8f;
    float inv = 1.0f/r;
    vhx[kk][i]=vx*inv; vhy[kk][i]=vy*inv; vhz[kk][i]=vz*inv;
    float u = r*0.2f;
    float env = 0.0f;
    if (u < 1.0f && i != k){
      float u2=u*u, u6=u2*u2*u2;
      env = 1.0f - 28.0f*u6 + 48.0f*u6*u - 21.0f*u6*u2;
    }
    float coef = 0.6324555320336759f * inv * env;
    float th   = r * 0.6283185307179586f;
    float s1 = __sinf(th), c1 = __cosf(th);
    float rb[NB];
    rb[0] = coef*s1;
    float twoc = 2.f*c1, sp = s1, spp = 0.f;
    #pragma unroll
    for(int n=1;n<NB;n++){ float s = twoc*sp - spp; spp = sp; sp = s; rb[n] = coef*s; }
    u16* hrow = hidB[kk] + i*HSTRB;
    #pragma unroll
    for(int jg=0;jg<16;jg++){
      float h0=0.f,h1=0.f,h2=0.f,h3=0.f;
      #pragma unroll
      for(int n=0;n<NB;n++){
        const float* wr = Wr1l + n*HID + jg*4;
        float rn = rb[n];
        h0 = fmaf(rn, wr[0], h0);
        h1 = fmaf(rn, wr[1], h1);
        h2 = fmaf(rn, wr[2], h2);
        h3 = fmaf(rn, wr[3], h3);
      }
      ushort4 uu = make_ushort4(f2bf(silu_f(h0)), f2bf(silu_f(h1)),
                                f2bf(silu_f(h2)), f2bf(silu_f(h3)));
      *(ushort4*)(hrow + jg*4) = uu;
    }
    if (tid < 3){
      float a0=0.f, a1=0.f;
      for (int n=0;n<NN;n+=2){ a0 += pb[n*3+tid]; a1 += pb[(n+1)*3+tid]; }
      comL[tid] = (a0+a1) * (1.0f/128.0f);
    }
  }
  __syncthreads();

  const float* sIb = sIn + b*FS*NN;
  const float* vIb = vIn + b*FV*3*NN;
  const float* tIb = tIn + b*FV*NN;
  const int i00 = sh*64 + quad*4;

#define MFMA_PAIR(accv, KK, MT) \
    { const int hrow_ = (sh*64 + (MT)*16 + col)*HSTRB + quad*8; \
      frag_ab a0_ = *(const frag_ab*)&hidB[KK][hrow_]; \
      frag_ab a1_ = *(const frag_ab*)&hidB[KK][hrow_ + 32]; \
      accv = __builtin_amdgcn_mfma_f32_16x16x32_bf16(a0_, b0, accv, 0,0,0); \
      accv = __builtin_amdgcn_mfma_f32_16x16x32_bf16(a1_, b1, accv, 0,0,0); }

  // q = 0,1 : m0a (factor = s[i][c], k-independent)
  #pragma unroll
  for (int q=0; q<2; q++){
    const int ntg = q*4 + wq;
    const int c   = ntg*16 + col;
    const u16* wp = w2bl + c*HID + quad*8;
    const frag_ab b0 = *(const frag_ab*)(wp);
    const frag_ab b1 = *(const frag_ab*)(wp + 32);
    const float* fb = sIb + c*NN + i00;
    float sA[4] = {0.f,0.f,0.f,0.f};
    #pragma unroll
    for (int mt=0; mt<4; mt++){
      float4 s4 = *(const float4*)&fb[mt*16];
      #pragma unroll
      for (int kk=0; kk<4; kk++){
        frag_cd acc = {0.f,0.f,0.f,0.f};
        MFMA_PAIR(acc, kk, mt);
        sA[kk] += acc[0]*s4.x + acc[1]*s4.y + acc[2]*s4.z + acc[3]*s4.w;
      }
    }
    #pragma unroll
    for (int kk=0; kk<4; kk++){
      float v = sA[kk];
      v += __shfl_xor(v, 16, 64); v += __shfl_xor(v, 32, 64);
      if (lane < 16) aggP[kk][sh][ntg*16+lane] = v;
    }
  }
  // q = 2 : m0b (factor = V[i,f,:]·vhat_k[i])
  {
    const int ntg = 8 + wq;
    const int c   = ntg*16 + col;
    const u16* wp = w2bl + c*HID + quad*8;
    const frag_ab b0 = *(const frag_ab*)(wp);
    const frag_ab b1 = *(const frag_ab*)(wp + 32);
    const int f = c - FS;
    const float* fb = vIb + f*3*NN + i00;
    float sA[4] = {0.f,0.f,0.f,0.f};
    #pragma unroll
    for (int mt=0; mt<4; mt++){
      float4 vx4 = *(const float4*)&fb[mt*16];
      float4 vy4 = *(const float4*)&fb[NN + mt*16];
      float4 vz4 = *(const float4*)&fb[2*NN + mt*16];
      #pragma unroll
      for (int kk=0; kk<4; kk++){
        float4 hx4 = *(const float4*)&vhx[kk][i00 + mt*16];
        float4 hy4 = *(const float4*)&vhy[kk][i00 + mt*16];
        float4 hz4 = *(const float4*)&vhz[kk][i00 + mt*16];
        frag_cd acc = {0.f,0.f,0.f,0.f};
        MFMA_PAIR(acc, kk, mt);
        sA[kk] += acc[0]*(vx4.x*hx4.x + vy4.x*hy4.x + vz4.x*hz4.x)
                + acc[1]*(vx4.y*hx4.y + vy4.y*hy4.y + vz4.y*hz4.y)
                + acc[2]*(vx4.z*hx4.z + vy4.z*hy4.z + vz4.z*hz4.z)
                + acc[3]*(vx4.w*hx4.w + vy4.w*hy4.w + vz4.w*hz4.w);
      }
    }
    #pragma unroll
    for (int kk=0; kk<4; kk++){
      float v = sA[kk];
      v += __shfl_xor(v, 16, 64); v += __shfl_xor(v, 32, 64);
      if (lane < 16) aggP[kk][sh][ntg*16+lane] = v;
    }
  }
  // q = 3 : m1a (tb = H * t[i,f]; 3 comps via vhat_k)
  {
    const int ntg = 12 + wq;
    const int c   = ntg*16 + col;
    const u16* wp = w2bl + c*HID + quad*8;
    const frag_ab b0 = *(const frag_ab*)(wp);
    const frag_ab b1 = *(const frag_ab*)(wp + 32);
    const int f = c - (FS+FV);
    const float* fb = tIb + f*NN + i00;
    float sX[4]={0.f,0.f,0.f,0.f}, sY[4]={0.f,0.f,0.f,0.f}, sZ[4]={0.f,0.f,0.f,0.f};
    #pragma unroll
    for (int mt=0; mt<4; mt++){
      float4 t4 = *(const float4*)&fb[mt*16];
      #pragma unroll
      for (int kk=0; kk<4; kk++){
        float4 hx4 = *(const float4*)&vhx[kk][i00 + mt*16];
        float4 hy4 = *(const float4*)&vhy[kk][i00 + mt*16];
        float4 hz4 = *(const float4*)&vhz[kk][i00 + mt*16];
        frag_cd acc = {0.f,0.f,0.f,0.f};
        MFMA_PAIR(acc, kk, mt);
        float t0_=acc[0]*t4.x, t1_=acc[1]*t4.y, t2_=acc[2]*t4.z, t3_=acc[3]*t4.w;
        sX[kk] += t0_*hx4.x + t1_*hx4.y + t2_*hx4.z + t3_*hx4.w;
        sY[kk] += t0_*hy4.x + t1_*hy4.y + t2_*hy4.z + t3_*hy4.w;
        sZ[kk] += t0_*hz4.x + t1_*hz4.y + t2_*hz4.z + t3_*hz4.w;
      }
    }
    #pragma unroll
    for (int kk=0; kk<4; kk++){
      float x = sX[kk]; x += __shfl_xor(x,16,64); x += __shfl_xor(x,32,64);
      float y = sY[kk]; y += __shfl_xor(y,16,64); y += __shfl_xor(y,32,64);
      float z = sZ[kk]; z += __shfl_xor(z,16,64); z += __shfl_xor(z,32,64);
      if (lane < 16){
        const int f2 = (ntg*16 + lane) - 192;
        aggP[kk][sh][192+f2*3+0]=x; aggP[kk][sh][192+f2*3+1]=y; aggP[kk][sh][192+f2*3+2]=z;
      }
    }
  }
  // q = 4 : m1b (factor = V[i,f,c3], k-independent; H differs per k)
  {
    const int ntg = 16 + wq;
    const int c   = ntg*16 + col;
    const u16* wp = w2bl + c*HID + quad*8;
    const frag_ab b0 = *(const frag_ab*)(wp);
    const frag_ab b1 = *(const frag_ab*)(wp + 32);
    const int f = c - (FS+2*FV);
    const float* fb = vIb + f*3*NN + i00;
    float sX[4]={0.f,0.f,0.f,0.f}, sY[4]={0.f,0.f,0.f,0.f}, sZ[4]={0.f,0.f,0.f,0.f};
    #pragma unroll
    for (int mt=0; mt<4; mt++){
      float4 vx4 = *(const float4*)&fb[mt*16];
      float4 vy4 = *(const float4*)&fb[NN + mt*16];
      float4 vz4 = *(const float4*)&fb[2*NN + mt*16];
      #pragma unroll
      for (int kk=0; kk<4; kk++){
        frag_cd acc = {0.f,0.f,0.f,0.f};
        MFMA_PAIR(acc, kk, mt);
        sX[kk] += acc[0]*vx4.x + acc[1]*vx4.y + acc[2]*vx4.z + acc[3]*vx4.w;
        sY[kk] += acc[0]*vy4.x + acc[1]*vy4.y + acc[2]*vy4.z + acc[3]*vy4.w;
        sZ[kk] += acc[0]*vz4.x + acc[1]*vz4.y + acc[2]*vz4.z + acc[3]*vz4.w;
      }
    }
    #pragma unroll
    for (int kk=0; kk<4; kk++){
      float x = sX[kk]; x += __shfl_xor(x,16,64); x += __shfl_xor(x,32,64);
      float y = sY[kk]; y += __shfl_xor(y,16,64); y += __shfl_xor(y,32,64);
      float z = sZ[kk]; z += __shfl_xor(z,16,64); z += __shfl_xor(z,32,64);
      if (lane < 16){
        const int f2 = (ntg*16 + lane) - 256;
        aggP[kk][sh][384+f2*3+0]=x; aggP[kk][sh][384+f2*3+1]=y; aggP[kk][sh][384+f2*3+2]=z;
      }
    }
  }
#undef MFMA_PAIR

  __syncthreads();
  for (int t2=tid; t2<2304; t2+=512){
    const int kk = t2 / 576;
    const int t  = t2 - kk*576;
    aggP[kk][0][t] = (aggP[kk][0][t] + aggP[kk][1][t]) * (1.0f/128.0f);
  }
  __syncthreads();

  // ---- E1: s-mix partials (tid<256) | V-mix (tid 256..447); weights loaded once ----
  if (tid < 256){
    const int o = tid & 127, p = tid >> 7;
    const int c0 = p*96;
    float a0=0.f,a1=0.f,a2=0.f,a3=0.f;
    #pragma unroll 8
    for (int cc=c0; cc<c0+96; cc++){
      float w0 = WmixSl[cc*FS+o];
      a0 = fmaf(aggP[0][0][cc], w0, a0);
      a1 = fmaf(aggP[1][0][cc], w0, a1);
      a2 = fmaf(aggP[2][0][cc], w0, a2);
      a3 = fmaf(aggP[3][0][cc], w0, a3);
    }
    sPart[0][p][o] = a0; sPart[1][p][o] = a1;
    sPart[2][p][o] = a2; sPart[3][p][o] = a3;
  } else if (tid < 448){
    const int o = tid - 256;
    const int g = o/3, c3 = o - g*3;
    float a0=0.f,a1=0.f,a2=0.f,a3=0.f;
    #pragma unroll 8
    for (int f=0; f<FV; f++){
      float w0 = WmixVl[f*FV+g];
      float w1 = WmixVl[(f+FV)*FV+g];
      a0 = fmaf(aggP[0][0][192+f*3+c3], w0, a0); a0 = fmaf(aggP[0][0][384+f*3+c3], w1, a0);
      a1 = fmaf(aggP[1][0][192+f*3+c3], w0, a1); a1 = fmaf(aggP[1][0][384+f*3+c3], w1, a1);
      a2 = fmaf(aggP[2][0][192+f*3+c3], w0, a2); a2 = fmaf(aggP[2][0][384+f*3+c3], w1, a2);
      a3 = fmaf(aggP[3][0][192+f*3+c3], w0, a3); a3 = fmaf(aggP[3][0][384+f*3+c3], w1, a3);
    }
    vNewL[0][o] = vIb[o*NN + k0]     + a0;
    vNewL[1][o] = vIb[o*NN + k0 + 1] + a1;
    vNewL[2][o] = vIb[o*NN + k0 + 2] + a2;
    vNewL[3][o] = vIb[o*NN + k0 + 3] + a3;
  }
  __syncthreads();

  // ---- E2: s-finalize (tid<128) | out_v (tid 128..319) ----
  if (tid < FS){
    #pragma unroll
    for (int kk=0; kk<4; kk++)
      sNew[kk][tid] = sIb[tid*NN + k0 + kk] + silu_f(sPart[kk][0][tid] + sPart[kk][1][tid]);
  } else if (tid < 320){
    const int o = tid - 128;
    const int g = o/3, c3 = o - g*3;
    float a0 = comL[c3], a1 = comL[c3], a2 = comL[c3], a3 = comL[c3];
    #pragma unroll 8
    for (int f=0; f<FV; f++){
      float wv = WoutV[f*FV+g];
      a0 = fmaf(vNewL[0][f*3+c3], wv, a0);
      a1 = fmaf(vNewL[1][f*3+c3], wv, a1);
      a2 = fmaf(vNewL[2][f*3+c3], wv, a2);
      a3 = fmaf(vNewL[3][f*3+c3], wv, a3);
    }
    outp[(b*NN+k0)*FV*3 + o]   = a0;
    outp[(b*NN+k0+1)*FV*3 + o] = a1;
    outp[(b*NN+k0+2)*FV*3 + o] = a2;
    outp[(b*NN+k0+3)*FV*3 + o] = a3;
  }
  __syncthreads();

  // ---- E3: out_s (tid<128) ----
  if (tid < FS){
    float a0=0.f,a1=0.f,a2=0.f,a3=0.f;
    #pragma unroll 8
    for (int f=0; f<FS; f++){
      float w0 = WoutS[f*FS+tid];
      a0 = fmaf(sNew[0][f], w0, a0);
      a1 = fmaf(sNew[1][f], w0, a1);
      a2 = fmaf(sNew[2][f], w0, a2);
      a3 = fmaf(sNew[3][f], w0, a3);
    }
    outp[BATCH*NN*FV*3 + (b*NN+k0)*FS + tid]   = a0;
    outp[BATCH*NN*FV*3 + (b*NN+k0+1)*FS + tid] = a1;
    outp[BATCH*NN*FV*3 + (b*NN+k0+2)*FS + tid] = a2;
    outp[BATCH*NN*FV*3 + (b*NN+k0+3)*FS + tid] = a3;
  }
}

extern "C" void kernel_launch(void* const* d_in, const int* in_sizes, int n_in,
                              void* d_out, int out_size, void* d_ws, size_t ws_size,
                              hipStream_t stream)
{
  const float* x       = (const float*)d_in[0];
  const float* species = (const float*)d_in[1];
  const float* Wr1     = (const float*)d_in[2];
  const float* Wr2     = (const float*)d_in[3];
  const float* Wsv     = (const float*)d_in[4];
  const float* WmixS   = (const float*)d_in[5];
  const float* WmixV   = (const float*)d_in[6];
  const float* WoutS   = (const float*)d_in[7];
  const float* WoutV   = (const float*)d_in[8];
  float* ws  = (float*)d_ws;
  float* out = (float*)d_out;

  float* sB  = ws + OFF_SB;
  float* vB  = ws + OFF_VB;
  float* t1  = ws + OFF_T1;
  u16*   w2b = (u16*)(ws + OFF_W2B);

  // layer 0 (specialized, 4 receivers/block) -> sB, vB, t1; also Wr2[layer1] -> w2b bf16
  layer0_kernel<<<BATCH*NN/4, 512, 0, stream>>>(x, species, Wr1, Wr2, Wsv,
      WmixS, WmixV, sB, vB, t1, w2b);

  // layer 1 (final, 4 receivers/block): writes d_out directly
  layer_kernel<<<BATCH*NN/4, 512, 0, stream>>>(x, sB, vB, t1,
      Wr1 + NB*HID, w2b, WmixS + 192*FS, WmixV + 128*FV,
      WoutS, WoutV, out);
}

// Round 17
// 127.535 us; speedup vs baseline: 1.0494x; 1.0494x over previous
//
#include <hip/hip_runtime.h>
#include <math.h>

typedef unsigned short u16;
typedef __attribute__((ext_vector_type(8))) short frag_ab;  // 8 bf16
typedef __attribute__((ext_vector_type(4))) float frag_cd;  // 4 fp32

#define BATCH 8
#define NN 128
#define FS 128
#define FV 64
#define NB 8
#define HID 64
#define ROUT 320
#define HSTRB 72    // hid bf16 LDS row stride (shorts)

// ---- ws layout (float offsets); s:[b][f][n], V:[b][f*3+c3][n], t:[b][g][n] ----
#define SZ_S (BATCH*FS*NN)
#define SZ_V (BATCH*FV*3*NN)
#define SZ_T (BATCH*FV*NN)
#define N_W2B (ROUT*HID)            // ushort count (layer-1 Wr2 in bf16)
#define OFF_SB 0
#define OFF_VB (OFF_SB+SZ_S)
#define OFF_T1 (OFF_VB+SZ_V)
#define OFF_W2B (OFF_T1+SZ_T)

__device__ __forceinline__ float silu_f(float x){ return x * (1.0f/(1.0f + __expf(-x))); }

__device__ __forceinline__ u16 f2bf(float x){
  union { float f; unsigned int u; } v; v.f = x;
  unsigned int r = v.u + 0x7fffu + ((v.u >> 16) & 1u);
  return (u16)(r >> 16);
}
__device__ __forceinline__ float bf2f(u16 h){
  union { unsigned int u; float f; } v; v.u = ((unsigned int)h) << 16; return v.f;
}

// ---------------- Layer 0 (specialized): TWO receivers per block (R14 proven best) ----------------
__global__ __launch_bounds__(512) void layer0_kernel(
    const float* __restrict__ pos,
    const float* __restrict__ species,  // (128)
    const float* __restrict__ Wr1l,     // (8,64) layer0
    const float* __restrict__ Wr2,      // (2,64,320) fp32
    const float* __restrict__ Wsv,      // (2,128,64)
    const float* __restrict__ WmixSl,   // (192,128) layer0
    const float* __restrict__ WmixVl,   // (128,64) layer0
    float* __restrict__ sOut,           // [b][f][n]
    float* __restrict__ vOut,           // [b][f*3+c3][n]
    float* __restrict__ tOut,           // [b][g][n]
    u16*   __restrict__ w2b)            // (320,64) bf16 c-major, layer1
{
  const int tid = threadIdx.x;
  const int b   = blockIdx.x >> 6;
  const int k0  = (blockIdx.x & 63) * 2;

  __shared__ u16   hidB[2][128*HSTRB];
  __shared__ float vhx[2][128], vhy[2][128], vhz[2][128];
  __shared__ float colsum[2][4][64];
  __shared__ float aggS[2][128];
  __shared__ float dV[2][192];
  __shared__ float sNew[2][128];
  __shared__ float t0L[64];

  const float* pb   = pos + b*NN*3;
  const float* Wr2l = Wr2;

  {
    const int kk   = tid >> 8;
    const int r2   = tid & 255;
    const int i    = r2 & 127;
    const int half = r2 >> 7;
    const int k    = k0 + kk;
    float vx = pb[k*3+0]-pb[i*3+0];
    float vy = pb[k*3+1]-pb[i*3+1];
    float vz = pb[k*3+2]-pb[i*3+2];
    float r = sqrtf(vx*vx+vy*vy+vz*vz) + 1e-8f;
    float inv = 1.0f/r;
    if (half==0){ vhx[kk][i]=vx*inv; vhy[kk][i]=vy*inv; vhz[kk][i]=vz*inv; }
    float u = r*0.2f;
    float env = 0.0f;
    if (u < 1.0f && i != k){
      float u2=u*u, u6=u2*u2*u2;
      env = 1.0f - 28.0f*u6 + 48.0f*u6*u - 21.0f*u6*u2;
    }
    float coef = 0.6324555320336759f * inv * env;
    float th   = r * 0.6283185307179586f;
    float s1 = __sinf(th), c1 = __cosf(th);
    float rb[NB];
    rb[0] = coef*s1;
    float twoc = 2.f*c1, sp = s1, spp = 0.f;
    #pragma unroll
    for(int n=1;n<NB;n++){ float s = twoc*sp - spp; spp = sp; sp = s; rb[n] = coef*s; }
    u16* hrow = hidB[kk] + i*HSTRB;
    #pragma unroll
    for(int jg=0;jg<8;jg++){
      const int jgg = half*8 + jg;
      float h0=0.f,h1=0.f,h2=0.f,h3=0.f;
      #pragma unroll
      for(int n=0;n<NB;n++){
        const float* wr = Wr1l + n*HID + jgg*4;
        float rn = rb[n];
        h0 = fmaf(rn, wr[0], h0);
        h1 = fmaf(rn, wr[1], h1);
        h2 = fmaf(rn, wr[2], h2);
        h3 = fmaf(rn, wr[3], h3);
      }
      ushort4 uu = make_ushort4(f2bf(silu_f(h0)), f2bf(silu_f(h1)),
                                f2bf(silu_f(h2)), f2bf(silu_f(h3)));
      *(ushort4*)(hrow + jgg*4) = uu;
    }
  }
  __syncthreads();

  {
    const int kk  = tid >> 8;
    const int var = (tid >> 6) & 3;
    const int j   = tid & 63;
    const u16* hb = hidB[kk];
    float a0 = 0.f, a1 = 0.f;
    if (var == 0){
      #pragma unroll 8
      for (int i=0;i<128;i+=2){
        a0 += bf2f(hb[i*HSTRB + j]);
        a1 += bf2f(hb[(i+1)*HSTRB + j]);
      }
    } else {
      const float* wv = (var==1) ? vhx[kk] : (var==2) ? vhy[kk] : vhz[kk];
      #pragma unroll 8
      for (int i=0;i<128;i+=2){
        a0 = fmaf(bf2f(hb[i*HSTRB + j]),     wv[i],   a0);
        a1 = fmaf(bf2f(hb[(i+1)*HSTRB + j]), wv[i+1], a1);
      }
    }
    colsum[kk][var][j] = a0+a1;
  }
  __syncthreads();

  if (tid < 128){
    const int c = tid;
    float d00=0.f,d01=0.f, d10=0.f,d11=0.f;
    #pragma unroll 8
    for (int j=0;j<HID;j+=2){
      float w0 = Wr2l[j*ROUT + c];
      float w1 = Wr2l[(j+1)*ROUT + c];
      d00 = fmaf(colsum[0][0][j],   w0, d00);
      d01 = fmaf(colsum[0][0][j+1], w1, d01);
      d10 = fmaf(colsum[1][0][j],   w0, d10);
      d11 = fmaf(colsum[1][0][j+1], w1, d11);
    }
    float sc = species[c] * (1.0f/128.0f);
    aggS[0][c] = sc * (d00+d01);
    aggS[1][c] = sc * (d10+d11);
  } else if (tid < 320){
    const int o = tid - 128;
    const int f = o & 63, c3 = o >> 6;
    float d00=0.f,d01=0.f, d10=0.f,d11=0.f;
    #pragma unroll 8
    for (int j=0;j<HID;j+=2){
      float w0 = Wr2l[j*ROUT + 192 + f];
      float w1 = Wr2l[(j+1)*ROUT + 192 + f];
      d00 = fmaf(colsum[0][1+c3][j],   w0, d00);
      d01 = fmaf(colsum[0][1+c3][j+1], w1, d01);
      d10 = fmaf(colsum[1][1+c3][j],   w0, d10);
      d11 = fmaf(colsum[1][1+c3][j+1], w1, d11);
    }
    dV[0][f*3+c3] = (d00+d01) * (1.0f/128.0f);
    dV[1][f*3+c3] = (d10+d11) * (1.0f/128.0f);
  } else if (tid < 384){
    const int g = tid - 320;
    float a0=0.f, a1=0.f;
    #pragma unroll 8
    for (int c=0; c<FS; c+=2){
      a0 = fmaf(species[c],   Wsv[c*FV+g],     a0);
      a1 = fmaf(species[c+1], Wsv[(c+1)*FV+g], a1);
    }
    t0L[g] = a0+a1;
  } else if (tid < 424){
    const int t = blockIdx.x*40 + (tid-384);
    const int j = t & 63, c = t >> 6;
    w2b[t] = f2bf(Wr2[HID*ROUT + j*ROUT + c]);
  }
  __syncthreads();

  if (tid < FS){
    float a00=0.f,a01=0.f, a10=0.f,a11=0.f;
    #pragma unroll 8
    for (int cc=0; cc<128; cc+=2){
      float w0 = WmixSl[cc*FS+tid];
      float w1 = WmixSl[(cc+1)*FS+tid];
      a00 = fmaf(aggS[0][cc],   w0, a00);
      a01 = fmaf(aggS[0][cc+1], w1, a01);
      a10 = fmaf(aggS[1][cc],   w0, a10);
      a11 = fmaf(aggS[1][cc+1], w1, a11);
    }
    float sn0 = species[tid] + silu_f(a00+a01);
    float sn1 = species[tid] + silu_f(a10+a11);
    sNew[0][tid] = sn0;
    sNew[1][tid] = sn1;
    sOut[(b*FS+tid)*NN + k0]     = sn0;
    sOut[(b*FS+tid)*NN + k0 + 1] = sn1;
  } else if (tid < 320){
    const int o = tid - 128;
    const int g = o/3, c3 = o - g*3;
    float a0=0.f, a1=0.f;
    #pragma unroll 8
    for (int f=0; f<FV; f++){
      float w = WmixVl[f*FV+g];
      float tf = t0L[f];
      a0 = fmaf(tf*dV[0][f*3+c3], w, a0);
      a1 = fmaf(tf*dV[1][f*3+c3], w, a1);
    }
    vOut[(b*FV*3 + o)*NN + k0]     = a0;
    vOut[(b*FV*3 + o)*NN + k0 + 1] = a1;
  }
  __syncthreads();

  if (tid < FV){
    const float* Wsv1 = Wsv + FS*FV;
    float a00=0.f,a01=0.f, a10=0.f,a11=0.f;
    #pragma unroll 8
    for (int f=0; f<FS; f+=2){
      float w0 = Wsv1[f*FV+tid];
      float w1 = Wsv1[(f+1)*FV+tid];
      a00 = fmaf(sNew[0][f],   w0, a00);
      a01 = fmaf(sNew[0][f+1], w1, a01);
      a10 = fmaf(sNew[1][f],   w0, a10);
      a11 = fmaf(sNew[1][f+1], w1, a11);
    }
    tOut[(b*FV+tid)*NN + k0]     = (a00+a01);
    tOut[(b*FV+tid)*NN + k0 + 1] = (a10+a11);
  }
}

// ---------------- Layer 1 (final): FOUR receivers per block (R15 proven best) ----------------
__global__ __launch_bounds__(512) void layer_kernel(
    const float* __restrict__ pos,
    const float* __restrict__ sIn,    // [b][f][n]
    const float* __restrict__ vIn,    // [b][f*3+c3][n]
    const float* __restrict__ tIn,    // [b][g][n]
    const float* __restrict__ Wr1l,   // (8,64) layer1
    const u16*   __restrict__ w2bl,   // (320,64) bf16, c-major
    const float* __restrict__ WmixSl, // (192,128)
    const float* __restrict__ WmixVl, // (128,64)
    const float* __restrict__ WoutS,
    const float* __restrict__ WoutV,
    float* __restrict__ outp)
{
  const int tid  = threadIdx.x;
  const int b    = blockIdx.x >> 5;
  const int k0   = (blockIdx.x & 31) * 4;     // receivers k0..k0+3
  const int w    = tid >> 6;
  const int lane = tid & 63;
  const int col  = lane & 15;
  const int quad = lane >> 4;
  const int wq   = w & 3;
  const int sh   = w >> 2;

  __shared__ u16   hidB[4][128*HSTRB];        // 73.7 KB
  __shared__ float vhx[4][128], vhy[4][128], vhz[4][128];
  __shared__ float aggP[4][2][576];           // 18.4 KB
  __shared__ float sPart[4][2][FS];
  __shared__ float sNew[4][FS];
  __shared__ float vNewL[4][192];
  __shared__ float comL[3];

  const float* pb = pos + b*NN*3;

  // ---- phase 0: tid = kk*128 + i; full hid row per thread ----
  {
    const int kk = tid >> 7;
    const int i  = tid & 127;
    const int k  = k0 + kk;
    float vx = pb[k*3+0]-pb[i*3+0];
    float vy = pb[k*3+1]-pb[i*3+1];
    float vz = pb[k*3+2]-pb[i*3+2];
    float r = sqrtf(vx*vx+vy*vy+vz*vz) + 1e-8f;
    float inv = 1.0f/r;
    vhx[kk][i]=vx*inv; vhy[kk][i]=vy*inv; vhz[kk][i]=vz*inv;
    float u = r*0.2f;
    float env = 0.0f;
    if (u < 1.0f && i != k){
      float u2=u*u, u6=u2*u2*u2;
      env = 1.0f - 28.0f*u6 + 48.0f*u6*u - 21.0f*u6*u2;
    }
    float coef = 0.6324555320336759f * inv * env;
    float th   = r * 0.6283185307179586f;
    float s1 = __sinf(th), c1 = __cosf(th);
    float rb[NB];
    rb[0] = coef*s1;
    float twoc = 2.f*c1, sp = s1, spp = 0.f;
    #pragma unroll
    for(int n=1;n<NB;n++){ float s = twoc*sp - spp; spp = sp; sp = s; rb[n] = coef*s; }
    u16* hrow = hidB[kk] + i*HSTRB;
    #pragma unroll
    for(int jg=0;jg<16;jg++){
      float h0=0.f,h1=0.f,h2=0.f,h3=0.f;
      #pragma unroll
      for(int n=0;n<NB;n++){
        const float* wr = Wr1l + n*HID + jg*4;
        float rn = rb[n];
        h0 = fmaf(rn, wr[0], h0);
        h1 = fmaf(rn, wr[1], h1);
        h2 = fmaf(rn, wr[2], h2);
        h3 = fmaf(rn, wr[3], h3);
      }
      ushort4 uu = make_ushort4(f2bf(silu_f(h0)), f2bf(silu_f(h1)),
                                f2bf(silu_f(h2)), f2bf(silu_f(h3)));
      *(ushort4*)(hrow + jg*4) = uu;
    }
    if (tid < 3){
      float a0=0.f, a1=0.f;
      for (int n=0;n<NN;n+=2){ a0 += pb[n*3+tid]; a1 += pb[(n+1)*3+tid]; }
      comL[tid] = (a0+a1) * (1.0f/128.0f);
    }
  }
  __syncthreads();

  const float* sIb = sIn + b*FS*NN;
  const float* vIb = vIn + b*FV*3*NN;
  const float* tIb = tIn + b*FV*NN;
  const int i00 = sh*64 + quad*4;

#define MFMA_PAIR(accv, KK, MT) \
    { const int hrow_ = (sh*64 + (MT)*16 + col)*HSTRB + quad*8; \
      frag_ab a0_ = *(const frag_ab*)&hidB[KK][hrow_]; \
      frag_ab a1_ = *(const frag_ab*)&hidB[KK][hrow_ + 32]; \
      accv = __builtin_amdgcn_mfma_f32_16x16x32_bf16(a0_, b0, accv, 0,0,0); \
      accv = __builtin_amdgcn_mfma_f32_16x16x32_bf16(a1_, b1, accv, 0,0,0); }

  // q = 0,1 : m0a (factor = s[i][c], k-independent)
  #pragma unroll
  for (int q=0; q<2; q++){
    const int ntg = q*4 + wq;
    const int c   = ntg*16 + col;
    const u16* wp = w2bl + c*HID + quad*8;
    const frag_ab b0 = *(const frag_ab*)(wp);
    const frag_ab b1 = *(const frag_ab*)(wp + 32);
    const float* fb = sIb + c*NN + i00;
    float sA[4] = {0.f,0.f,0.f,0.f};
    #pragma unroll
    for (int mt=0; mt<4; mt++){
      float4 s4 = *(const float4*)&fb[mt*16];
      #pragma unroll
      for (int kk=0; kk<4; kk++){
        frag_cd acc = {0.f,0.f,0.f,0.f};
        MFMA_PAIR(acc, kk, mt);
        sA[kk] += acc[0]*s4.x + acc[1]*s4.y + acc[2]*s4.z + acc[3]*s4.w;
      }
    }
    #pragma unroll
    for (int kk=0; kk<4; kk++){
      float v = sA[kk];
      v += __shfl_xor(v, 16, 64); v += __shfl_xor(v, 32, 64);
      if (lane < 16) aggP[kk][sh][ntg*16+lane] = v;
    }
  }
  // q = 2 : m0b (factor = V[i,f,:]·vhat_k[i])
  {
    const int ntg = 8 + wq;
    const int c   = ntg*16 + col;
    const u16* wp = w2bl + c*HID + quad*8;
    const frag_ab b0 = *(const frag_ab*)(wp);
    const frag_ab b1 = *(const frag_ab*)(wp + 32);
    const int f = c - FS;
    const float* fb = vIb + f*3*NN + i00;
    float sA[4] = {0.f,0.f,0.f,0.f};
    #pragma unroll
    for (int mt=0; mt<4; mt++){
      float4 vx4 = *(const float4*)&fb[mt*16];
      float4 vy4 = *(const float4*)&fb[NN + mt*16];
      float4 vz4 = *(const float4*)&fb[2*NN + mt*16];
      #pragma unroll
      for (int kk=0; kk<4; kk++){
        float4 hx4 = *(const float4*)&vhx[kk][i00 + mt*16];
        float4 hy4 = *(const float4*)&vhy[kk][i00 + mt*16];
        float4 hz4 = *(const float4*)&vhz[kk][i00 + mt*16];
        frag_cd acc = {0.f,0.f,0.f,0.f};
        MFMA_PAIR(acc, kk, mt);
        sA[kk] += acc[0]*(vx4.x*hx4.x + vy4.x*hy4.x + vz4.x*hz4.x)
                + acc[1]*(vx4.y*hx4.y + vy4.y*hy4.y + vz4.y*hz4.y)
                + acc[2]*(vx4.z*hx4.z + vy4.z*hy4.z + vz4.z*hz4.z)
                + acc[3]*(vx4.w*hx4.w + vy4.w*hy4.w + vz4.w*hz4.w);
      }
    }
    #pragma unroll
    for (int kk=0; kk<4; kk++){
      float v = sA[kk];
      v += __shfl_xor(v, 16, 64); v += __shfl_xor(v, 32, 64);
      if (lane < 16) aggP[kk][sh][ntg*16+lane] = v;
    }
  }
  // q = 3 : m1a (tb = H * t[i,f]; 3 comps via vhat_k)
  {
    const int ntg = 12 + wq;
    const int c   = ntg*16 + col;
    const u16* wp = w2bl + c*HID + quad*8;
    const frag_ab b0 = *(const frag_ab*)(wp);
    const frag_ab b1 = *(const frag_ab*)(wp + 32);
    const int f = c - (FS+FV);
    const float* fb = tIb + f*NN + i00;
    float sX[4]={0.f,0.f,0.f,0.f}, sY[4]={0.f,0.f,0.f,0.f}, sZ[4]={0.f,0.f,0.f,0.f};
    #pragma unroll
    for (int mt=0; mt<4; mt++){
      float4 t4 = *(const float4*)&fb[mt*16];
      #pragma unroll
      for (int kk=0; kk<4; kk++){
        float4 hx4 = *(const float4*)&vhx[kk][i00 + mt*16];
        float4 hy4 = *(const float4*)&vhy[kk][i00 + mt*16];
        float4 hz4 = *(const float4*)&vhz[kk][i00 + mt*16];
        frag_cd acc = {0.f,0.f,0.f,0.f};
        MFMA_PAIR(acc, kk, mt);
        float t0_=acc[0]*t4.x, t1_=acc[1]*t4.y, t2_=acc[2]*t4.z, t3_=acc[3]*t4.w;
        sX[kk] += t0_*hx4.x + t1_*hx4.y + t2_*hx4.z + t3_*hx4.w;
        sY[kk] += t0_*hy4.x + t1_*hy4.y + t2_*hy4.z + t3_*hy4.w;
        sZ[kk] += t0_*hz4.x + t1_*hz4.y + t2_*hz4.z + t3_*hz4.w;
      }
    }
    #pragma unroll
    for (int kk=0; kk<4; kk++){
      float x = sX[kk]; x += __shfl_xor(x,16,64); x += __shfl_xor(x,32,64);
      float y = sY[kk]; y += __shfl_xor(y,16,64); y += __shfl_xor(y,32,64);
      float z = sZ[kk]; z += __shfl_xor(z,16,64); z += __shfl_xor(z,32,64);
      if (lane < 16){
        const int f2 = (ntg*16 + lane) - 192;
        aggP[kk][sh][192+f2*3+0]=x; aggP[kk][sh][192+f2*3+1]=y; aggP[kk][sh][192+f2*3+2]=z;
      }
    }
  }
  // q = 4 : m1b (factor = V[i,f,c3], k-independent; H differs per k)
  {
    const int ntg = 16 + wq;
    const int c   = ntg*16 + col;
    const u16* wp = w2bl + c*HID + quad*8;
    const frag_ab b0 = *(const frag_ab*)(wp);
    const frag_ab b1 = *(const frag_ab*)(wp + 32);
    const int f = c - (FS+2*FV);
    const float* fb = vIb + f*3*NN + i00;
    float sX[4]={0.f,0.f,0.f,0.f}, sY[4]={0.f,0.f,0.f,0.f}, sZ[4]={0.f,0.f,0.f,0.f};
    #pragma unroll
    for (int mt=0; mt<4; mt++){
      float4 vx4 = *(const float4*)&fb[mt*16];
      float4 vy4 = *(const float4*)&fb[NN + mt*16];
      float4 vz4 = *(const float4*)&fb[2*NN + mt*16];
      #pragma unroll
      for (int kk=0; kk<4; kk++){
        frag_cd acc = {0.f,0.f,0.f,0.f};
        MFMA_PAIR(acc, kk, mt);
        sX[kk] += acc[0]*vx4.x + acc[1]*vx4.y + acc[2]*vx4.z + acc[3]*vx4.w;
        sY[kk] += acc[0]*vy4.x + acc[1]*vy4.y + acc[2]*vy4.z + acc[3]*vy4.w;
        sZ[kk] += acc[0]*vz4.x + acc[1]*vz4.y + acc[2]*vz4.z + acc[3]*vz4.w;
      }
    }
    #pragma unroll
    for (int kk=0; kk<4; kk++){
      float x = sX[kk]; x += __shfl_xor(x,16,64); x += __shfl_xor(x,32,64);
      float y = sY[kk]; y += __shfl_xor(y,16,64); y += __shfl_xor(y,32,64);
      float z = sZ[kk]; z += __shfl_xor(z,16,64); z += __shfl_xor(z,32,64);
      if (lane < 16){
        const int f2 = (ntg*16 + lane) - 256;
        aggP[kk][sh][384+f2*3+0]=x; aggP[kk][sh][384+f2*3+1]=y; aggP[kk][sh][384+f2*3+2]=z;
      }
    }
  }
#undef MFMA_PAIR

  __syncthreads();
  for (int t2=tid; t2<2304; t2+=512){
    const int kk = t2 / 576;
    const int t  = t2 - kk*576;
    aggP[kk][0][t] = (aggP[kk][0][t] + aggP[kk][1][t]) * (1.0f/128.0f);
  }
  __syncthreads();

  // ---- E1: s-mix partials (tid<256) | V-mix (tid 256..447); weights loaded once ----
  if (tid < 256){
    const int o = tid & 127, p = tid >> 7;
    const int c0 = p*96;
    float a0=0.f,a1=0.f,a2=0.f,a3=0.f;
    #pragma unroll 8
    for (int cc=c0; cc<c0+96; cc++){
      float w0 = WmixSl[cc*FS+o];
      a0 = fmaf(aggP[0][0][cc], w0, a0);
      a1 = fmaf(aggP[1][0][cc], w0, a1);
      a2 = fmaf(aggP[2][0][cc], w0, a2);
      a3 = fmaf(aggP[3][0][cc], w0, a3);
    }
    sPart[0][p][o] = a0; sPart[1][p][o] = a1;
    sPart[2][p][o] = a2; sPart[3][p][o] = a3;
  } else if (tid < 448){
    const int o = tid - 256;
    const int g = o/3, c3 = o - g*3;
    float a0=0.f,a1=0.f,a2=0.f,a3=0.f;
    #pragma unroll 8
    for (int f=0; f<FV; f++){
      float w0 = WmixVl[f*FV+g];
      float w1 = WmixVl[(f+FV)*FV+g];
      a0 = fmaf(aggP[0][0][192+f*3+c3], w0, a0); a0 = fmaf(aggP[0][0][384+f*3+c3], w1, a0);
      a1 = fmaf(aggP[1][0][192+f*3+c3], w0, a1); a1 = fmaf(aggP[1][0][384+f*3+c3], w1, a1);
      a2 = fmaf(aggP[2][0][192+f*3+c3], w0, a2); a2 = fmaf(aggP[2][0][384+f*3+c3], w1, a2);
      a3 = fmaf(aggP[3][0][192+f*3+c3], w0, a3); a3 = fmaf(aggP[3][0][384+f*3+c3], w1, a3);
    }
    vNewL[0][o] = vIb[o*NN + k0]     + a0;
    vNewL[1][o] = vIb[o*NN + k0 + 1] + a1;
    vNewL[2][o] = vIb[o*NN + k0 + 2] + a2;
    vNewL[3][o] = vIb[o*NN + k0 + 3] + a3;
  }
  __syncthreads();

  // ---- E2: s-finalize (tid<128) | out_v (tid 128..319) ----
  if (tid < FS){
    #pragma unroll
    for (int kk=0; kk<4; kk++)
      sNew[kk][tid] = sIb[tid*NN + k0 + kk] + silu_f(sPart[kk][0][tid] + sPart[kk][1][tid]);
  } else if (tid < 320){
    const int o = tid - 128;
    const int g = o/3, c3 = o - g*3;
    float a0 = comL[c3], a1 = comL[c3], a2 = comL[c3], a3 = comL[c3];
    #pragma unroll 8
    for (int f=0; f<FV; f++){
      float wv = WoutV[f*FV+g];
      a0 = fmaf(vNewL[0][f*3+c3], wv, a0);
      a1 = fmaf(vNewL[1][f*3+c3], wv, a1);
      a2 = fmaf(vNewL[2][f*3+c3], wv, a2);
      a3 = fmaf(vNewL[3][f*3+c3], wv, a3);
    }
    outp[(b*NN+k0)*FV*3 + o]   = a0;
    outp[(b*NN+k0+1)*FV*3 + o] = a1;
    outp[(b*NN+k0+2)*FV*3 + o] = a2;
    outp[(b*NN+k0+3)*FV*3 + o] = a3;
  }
  __syncthreads();

  // ---- E3: out_s (tid<128) ----
  if (tid < FS){
    float a0=0.f,a1=0.f,a2=0.f,a3=0.f;
    #pragma unroll 8
    for (int f=0; f<FS; f++){
      float w0 = WoutS[f*FS+tid];
      a0 = fmaf(sNew[0][f], w0, a0);
      a1 = fmaf(sNew[1][f], w0, a1);
      a2 = fmaf(sNew[2][f], w0, a2);
      a3 = fmaf(sNew[3][f], w0, a3);
    }
    outp[BATCH*NN*FV*3 + (b*NN+k0)*FS + tid]   = a0;
    outp[BATCH*NN*FV*3 + (b*NN+k0+1)*FS + tid] = a1;
    outp[BATCH*NN*FV*3 + (b*NN+k0+2)*FS + tid] = a2;
    outp[BATCH*NN*FV*3 + (b*NN+k0+3)*FS + tid] = a3;
  }
}

extern "C" void kernel_launch(void* const* d_in, const int* in_sizes, int n_in,
                              void* d_out, int out_size, void* d_ws, size_t ws_size,
                              hipStream_t stream)
{
  const float* x       = (const float*)d_in[0];
  const float* species = (const float*)d_in[1];
  const float* Wr1     = (const float*)d_in[2];
  const float* Wr2     = (const float*)d_in[3];
  const float* Wsv     = (const float*)d_in[4];
  const float* WmixS   = (const float*)d_in[5];
  const float* WmixV   = (const float*)d_in[6];
  const float* WoutS   = (const float*)d_in[7];
  const float* WoutV   = (const float*)d_in[8];
  float* ws  = (float*)d_ws;
  float* out = (float*)d_out;

  float* sB  = ws + OFF_SB;
  float* vB  = ws + OFF_VB;
  float* t1  = ws + OFF_T1;
  u16*   w2b = (u16*)(ws + OFF_W2B);

  // layer 0 (specialized, 2 receivers/block) -> sB, vB, t1; also Wr2[layer1] -> w2b bf16
  layer0_kernel<<<BATCH*NN/2, 512, 0, stream>>>(x, species, Wr1, Wr2, Wsv,
      WmixS, WmixV, sB, vB, t1, w2b);

  // layer 1 (final, 4 receivers/block): writes d_out directly
  layer_kernel<<<BATCH*NN/4, 512, 0, stream>>>(x, sB, vB, t1,
      Wr1 + NB*HID, w2b, WmixS + 192*FS, WmixV + 128*FV,
      WoutS, WoutV, out);
}